// Round 11
// baseline (1115.810 us; speedup 1.0000x reference)
//
#include <hip/hip_runtime.h>
#include <hip/hip_bf16.h>
#include <stdint.h>
#include <math.h>

#define NR 16384
#define DIM 768
#define KEPS 1e-8f

#define BM 128          // tile edge
#define BK 128          // staged K per tile (one x128 MFMA per frag pair)
#define NB (NR / BM)    // 128 row/col blocks
#define KT (DIM / BK)   // 6 k-tiles
#define NTILES (NB * (NB + 1) / 2)   // 8256 upper-triangle tiles

typedef __attribute__((ext_vector_type(4))) float f32x4;
typedef __attribute__((ext_vector_type(8))) int   i32x8;

__device__ inline uint32_t fkey(float f) {
    union { float f; uint32_t u; } v; v.f = f;
    return (v.u & 0x80000000u) ? ~v.u : (v.u | 0x80000000u);
}

__device__ inline unsigned long long pack_vc(float v, int c) {
    return ((unsigned long long)fkey(v) << 32) | (unsigned)c;
}

__device__ inline void gload16(const uint8_t* g, const uint8_t* l) {
    __builtin_amdgcn_global_load_lds(
        (const __attribute__((address_space(1))) void*)g,
        (__attribute__((address_space(3))) void*)l,
        16, 0, 0);
}

// fp32 -> OCP e4m3fn (selection only; refine pass recomputes exact fp32)
__device__ inline uint8_t f2fp8(float f) {
    union { float f; uint32_t u; } v; v.f = f;
    const uint8_t s = (uint8_t)((v.u >> 24) & 0x80u);
    float a = fabsf(f);
    if (a >= 448.0f) return s | 0x7E;
    if (a < 0.015625f) {
        int q = (int)rintf(a * 512.0f);
        if (q >= 8) return s | 0x08;
        return s | (uint8_t)q;
    }
    int ex; float m = frexpf(a, &ex);
    int E = ex + 6;
    int frac = (int)rintf(m * 16.0f - 8.0f);
    if (frac >= 8) { frac = 0; ++E; if (E > 15) return s | 0x7E; }
    return s | (uint8_t)(E << 3) | (uint8_t)frac;
}

// ---------- Kernel 1: row L2-normalize, fp32 -> fp8 (plain row-major) --------
__global__ __launch_bounds__(256) void k_norm(const float* __restrict__ X,
                                              uint8_t* __restrict__ Xn,
                                              float* __restrict__ norms) {
    __shared__ uint8_t buf[4][768];
    const int wid = threadIdx.x >> 6, lane = threadIdx.x & 63;
    const int row = blockIdx.x * 4 + wid;
    const float4* xr = (const float4*)(X + (size_t)row * DIM) + lane * 3;
    float4 a = xr[0], b = xr[1], c = xr[2];
    float s = a.x*a.x + a.y*a.y + a.z*a.z + a.w*a.w
            + b.x*b.x + b.y*b.y + b.z*b.z + b.w*b.w
            + c.x*c.x + c.y*c.y + c.z*c.z + c.w*c.w;
#pragma unroll
    for (int m = 32; m >= 1; m >>= 1) s += __shfl_xor(s, m);
    const float n = sqrtf(s);
    if (lane == 0) norms[row] = n;
    const float rn = 1.0f / fmaxf(n, KEPS);
    float v[12] = {a.x,a.y,a.z,a.w,b.x,b.y,b.z,b.w,c.x,c.y,c.z,c.w};
    uint8_t q[12];
#pragma unroll
    for (int i = 0; i < 12; ++i) q[i] = f2fp8(v[i] * rn);
    uint32_t* lb = (uint32_t*)&buf[wid][lane * 12];
    lb[0] = (uint32_t)q[0] | ((uint32_t)q[1] << 8) | ((uint32_t)q[2]  << 16) | ((uint32_t)q[3]  << 24);
    lb[1] = (uint32_t)q[4] | ((uint32_t)q[5] << 8) | ((uint32_t)q[6]  << 16) | ((uint32_t)q[7]  << 24);
    lb[2] = (uint32_t)q[8] | ((uint32_t)q[9] << 8) | ((uint32_t)q[10] << 16) | ((uint32_t)q[11] << 24);
    __syncthreads();
    if (lane < 48)
        *(uint4*)(Xn + (size_t)row * DIM + lane * 16) = *(const uint4*)&buf[wid][lane * 16];
}

// ---------------- Kernel 1b: init (value, index) max keys --------------------
__global__ __launch_bounds__(256) void k_init(unsigned long long* __restrict__ nn64) {
    nn64[blockIdx.x * 256 + threadIdx.x] = pack_vc(-2.0f, 0);
}

// ---- Kernel 2: MX-fp8 (scale=1.0) 128^2 upper-tri tile, BK=128, 6 rounds ----
// mfma_scale_f32_16x16x128_f8f6f4 with e8m0 scale 0x7F (=2^0) == exact plain
// fp8 dot. Correct for ANY shared k-permutation of A/B frags (dot invariant;
// uniform scale kills block-boundary concerns). LDS [128][128B]/panel, chunk
// swizzle c^=r&7 (16-lane group -> 8 positions x2 = free 2-way); source
// pre-swizzled, global_load_lds dest linear. Halves MFMA-pipe cyc per K-byte
// AND barrier/fetch rounds (12 -> 6) vs R10.
__global__ __launch_bounds__(256, 3) void k_maxdot(const uint8_t* __restrict__ Xn,
                                                   unsigned long long* __restrict__ nn64) {
    __shared__ uint8_t lA[BM * BK];
    __shared__ uint8_t lB[BM * BK];
    const int tid  = threadIdx.x;
    const int lane = tid & 63, wid = tid >> 6;
    const int wr = wid >> 1, wc = wid & 1;
    const int l15 = lane & 15, lhi = lane >> 4;

    // XCD-chunked bijective swizzle (NTILES % 8 == 0)
    int t = (int)blockIdx.x;
    t = (t & 7) * (NTILES / 8) + (t >> 3);
    // decode tile id -> (rb, cb), cb >= rb   [S(rb) = rb*(257-rb)/2]
    float disc = 66049.0f - 8.0f * (float)t;
    int rb = (int)((257.0f - sqrtf(disc)) * 0.5f);
    if (rb > NB - 1) rb = NB - 1;
    if (rb < 0) rb = 0;
    while (rb > 0 && rb * (257 - rb) / 2 > t) --rb;
    while ((rb + 1) * (257 - (rb + 1)) / 2 <= t) ++rb;
    const int cb = rb + (t - rb * (257 - rb) / 2);
    const int rowbase = rb * BM;
    const int colbase = cb * BM;
    const bool diag = (rb == cb);

    f32x4 acc[4][4];
    const f32x4 z = {0.f, 0.f, 0.f, 0.f};
#pragma unroll
    for (int i = 0; i < 4; ++i)
#pragma unroll
        for (int j = 0; j < 4; ++j) acc[i][j] = z;

    // staging: 4 issues per panel; thread covers row r = it*32 + tid/8,
    // chunk tid&7; source chunk pre-swizzled by r&7, LDS dest linear.
    const int s_r0 = tid >> 3;                 // 0..31
    const int s_c  = tid & 7;

    // swizzled 32B fragment read: row r, k-quarter lhi of a [128][128] region
    auto RDF = [&](const uint8_t* base, int r) -> i32x8 {
        const int rs = r & 7;
        const uint8_t* p = base + r * BK;
        const int4 lo = *(const int4*)(p + ((((lhi << 1))     ^ rs) << 4));
        const int4 hi = *(const int4*)(p + ((((lhi << 1) | 1) ^ rs) << 4));
        i32x8 v;
        v[0] = lo.x; v[1] = lo.y; v[2] = lo.z; v[3] = lo.w;
        v[4] = hi.x; v[5] = hi.y; v[6] = hi.z; v[7] = hi.w;
        return v;
    };

    for (int kt = 0; kt < KT; ++kt) {
#pragma unroll
        for (int it = 0; it < 4; ++it) {
            const int r = it * 32 + s_r0;
            const int c = s_c ^ (r & 7);
            const size_t koff = (size_t)kt * BK + c * 16;
            gload16(Xn + (size_t)(rowbase + r) * DIM + koff, lA + it * 4096 + tid * 16);
            gload16(Xn + (size_t)(colbase + r) * DIM + koff, lB + it * 4096 + tid * 16);
        }
        __syncthreads();     // vmcnt(0)+lgkmcnt(0) drain; co-resident blocks cover
        i32x8 af[4], bg[4];
#pragma unroll
        for (int mf = 0; mf < 4; ++mf) af[mf] = RDF(lA, wr * 64 + mf * 16 + l15);
#pragma unroll
        for (int nf = 0; nf < 4; ++nf) bg[nf] = RDF(lB, wc * 64 + nf * 16 + l15);
#pragma unroll
        for (int mf = 0; mf < 4; ++mf)
#pragma unroll
            for (int nf = 0; nf < 4; ++nf)
                acc[mf][nf] = __builtin_amdgcn_mfma_scale_f32_16x16x128_f8f6f4(
                    af[mf], bg[nf], acc[mf][nf],
                    0, 0,              // cbsz = fp8 e4m3, blgp = fp8 e4m3
                    0, 0x7F,           // opsel_a, scale_a = e8m0 1.0
                    0, 0x7F);          // opsel_b, scale_b = e8m0 1.0
        __syncthreads();
    }

    // diagonal tiles: mask self-similarity to -1 (reference semantics)
    if (diag) {
#pragma unroll
        for (int mf = 0; mf < 4; ++mf)
#pragma unroll
            for (int nf = 0; nf < 4; ++nf)
#pragma unroll
                for (int rr = 0; rr < 4; ++rr) {
                    const int rl = wr * 64 + mf * 16 + lhi * 4 + rr;
                    const int cl = wc * 64 + nf * 16 + l15;
                    if (rl == cl) acc[mf][nf][rr] = -1.0f;
                }
    }

    // ---- row-max with argmax col: nf regs -> 16 cols (lane bits 0..3) ----
#pragma unroll
    for (int mf = 0; mf < 4; ++mf)
#pragma unroll
        for (int rr = 0; rr < 4; ++rr) {
            float v = acc[mf][0][rr];
            int   c = colbase + wc * 64 + l15;
#pragma unroll
            for (int nf = 1; nf < 4; ++nf) {
                const float w2 = acc[mf][nf][rr];
                const int   c2 = colbase + wc * 64 + nf * 16 + l15;
                if (w2 > v) { v = w2; c = c2; }
            }
#pragma unroll
            for (int m = 1; m <= 8; m <<= 1) {
                const float ov = __shfl_xor(v, m);
                const int   oc = __shfl_xor(c, m);
                if (ov > v) { v = ov; c = oc; }
            }
            if (l15 == 0) {
                const int r = rowbase + wr * 64 + mf * 16 + lhi * 4 + rr;
                atomicMax(&nn64[r], pack_vc(v, c));
            }
        }

    // ---- col-max with argmax row: mf,rr regs -> row-groups (bits 4,5) ----
#pragma unroll
    for (int nf = 0; nf < 4; ++nf) {
        float v = acc[0][nf][0];
        int   c = rowbase + wr * 64 + lhi * 4;
#pragma unroll
        for (int mf = 0; mf < 4; ++mf)
#pragma unroll
            for (int rr = 0; rr < 4; ++rr) {
                if (mf == 0 && rr == 0) continue;
                const float w2 = acc[mf][nf][rr];
                const int   c2 = rowbase + wr * 64 + mf * 16 + lhi * 4 + rr;
                if (w2 > v) { v = w2; c = c2; }
            }
#pragma unroll
        for (int m = 16; m <= 32; m <<= 1) {
            const float ov = __shfl_xor(v, m);
            const int   oc = __shfl_xor(c, m);
            if (ov > v) { v = ov; c = oc; }
        }
        if ((lane >> 4) == 0) {
            const int cc = colbase + wc * 64 + nf * 16 + l15;
            atomicMax(&nn64[cc], pack_vc(v, c));
        }
    }
}

// --- Kernel 3: fp32 exact refine — reference distance for selected neighbor --
__global__ __launch_bounds__(256) void k_refine(const float* __restrict__ X,
                                                const float* __restrict__ norms,
                                                const unsigned long long* __restrict__ nn64,
                                                float* __restrict__ logd) {
    const int wid = threadIdx.x >> 6, lane = threadIdx.x & 63;
    const int r = blockIdx.x * 4 + wid;
    const int j = (int)(nn64[r] & 0xFFFFu);
    const float rnr = 1.0f / fmaxf(norms[r], KEPS);
    const float rnj = 1.0f / fmaxf(norms[j], KEPS);
    const float4* xr = (const float4*)(X + (size_t)r * DIM) + lane * 3;
    const float4* xj = (const float4*)(X + (size_t)j * DIM) + lane * 3;
    float s = 0.0f;
#pragma unroll
    for (int i = 0; i < 3; ++i) {
        const float4 a = xr[i], b = xj[i];
        float d;
        d = a.x * rnr - b.x * rnj + KEPS; s = fmaf(d, d, s);
        d = a.y * rnr - b.y * rnj + KEPS; s = fmaf(d, d, s);
        d = a.z * rnr - b.z * rnj + KEPS; s = fmaf(d, d, s);
        d = a.w * rnr - b.w * rnj + KEPS; s = fmaf(d, d, s);
    }
#pragma unroll
    for (int m = 32; m >= 1; m >>= 1) s += __shfl_xor(s, m);
    if (lane == 0) logd[r] = logf(sqrtf(s) + KEPS);
}

// ---------------- Kernel 4: deterministic mean of log-distances --------------
__global__ __launch_bounds__(256) void k_loss(const float* __restrict__ logd,
                                              float* __restrict__ out) {
    float local = 0.0f;
    for (int r = threadIdx.x; r < NR; r += 256) local += logd[r];
#pragma unroll
    for (int m = 32; m >= 1; m >>= 1) local += __shfl_xor(local, m);
    __shared__ float red[4];
    const int lane = threadIdx.x & 63, wid = threadIdx.x >> 6;
    if (lane == 0) red[wid] = local;
    __syncthreads();
    if (threadIdx.x == 0)
        out[0] = -(red[0] + red[1] + red[2] + red[3]) / (float)NR;
}

extern "C" void kernel_launch(void* const* d_in, const int* in_sizes, int n_in,
                              void* d_out, int out_size, void* d_ws, size_t ws_size,
                              hipStream_t stream) {
    const float* X = (const float*)d_in[0];
    float* out = (float*)d_out;
    uint8_t* Xn = (uint8_t*)d_ws;                                  // 12.6 MiB fp8
    char* p = (char*)d_ws + (size_t)NR * DIM;
    float* norms = (float*)p;                 p += (size_t)NR * 4;
    unsigned long long* nn64 = (unsigned long long*)p; p += (size_t)NR * 8;
    float* logd = (float*)p;

    k_norm<<<NR / 4, 256, 0, stream>>>(X, Xn, norms);
    k_init<<<NR / 256, 256, 0, stream>>>(nn64);
    k_maxdot<<<NTILES, 256, 0, stream>>>(Xn, nn64);
    k_refine<<<NR / 4, 256, 0, stream>>>(X, norms, nn64, logd);
    k_loss<<<1, 256, 0, stream>>>(logd, out);
}

// Round 12
// 315.177 us; speedup vs baseline: 3.5403x; 3.5403x over previous
//
#include <hip/hip_runtime.h>
#include <hip/hip_bf16.h>
#include <stdint.h>
#include <math.h>

#define NR 16384
#define DIM 768
#define KEPS 1e-8f

#define BM 128          // tile edge
#define BK 128          // staged K per round (two 64-k halves)
#define NB (NR / BM)    // 128 row/col blocks
#define KT (DIM / BK)   // 6 rounds
#define NTILES (NB * (NB + 1) / 2)   // 8256 upper-triangle tiles

typedef __attribute__((ext_vector_type(4))) float f32x4;
typedef __attribute__((ext_vector_type(2))) long long2_t;

__device__ inline uint32_t fkey(float f) {
    union { float f; uint32_t u; } v; v.f = f;
    return (v.u & 0x80000000u) ? ~v.u : (v.u | 0x80000000u);
}

__device__ inline unsigned long long pack_vc(float v, int c) {
    return ((unsigned long long)fkey(v) << 32) | (unsigned)c;
}

__device__ inline void gload16(const uint8_t* g, const uint8_t* l) {
    __builtin_amdgcn_global_load_lds(
        (const __attribute__((address_space(1))) void*)g,
        (__attribute__((address_space(3))) void*)l,
        16, 0, 0);
}

// fp32 -> OCP e4m3fn (selection only; refine pass recomputes exact fp32)
__device__ inline uint8_t f2fp8(float f) {
    union { float f; uint32_t u; } v; v.f = f;
    const uint8_t s = (uint8_t)((v.u >> 24) & 0x80u);
    float a = fabsf(f);
    if (a >= 448.0f) return s | 0x7E;
    if (a < 0.015625f) {
        int q = (int)rintf(a * 512.0f);
        if (q >= 8) return s | 0x08;
        return s | (uint8_t)q;
    }
    int ex; float m = frexpf(a, &ex);
    int E = ex + 6;
    int frac = (int)rintf(m * 16.0f - 8.0f);
    if (frac >= 8) { frac = 0; ++E; if (E > 15) return s | 0x7E; }
    return s | (uint8_t)(E << 3) | (uint8_t)frac;
}

// ---- Kernel 1: row L2-normalize -> fp8, k-permuted layout: within each ------
// ---- 64-k block, orig byte (ks*32 + h*8 + b) stored at (h*16 + ks*8 + b) ----
// ---- so one ds_read_b128 delivers a lane's ks0 AND ks1 MFMA fragments. ------
__global__ __launch_bounds__(256) void k_norm(const float* __restrict__ X,
                                              uint8_t* __restrict__ Xn,
                                              float* __restrict__ norms) {
    __shared__ uint8_t buf[4][768];
    const int wid = threadIdx.x >> 6, lane = threadIdx.x & 63;
    const int row = blockIdx.x * 4 + wid;
    const float4* xr = (const float4*)(X + (size_t)row * DIM) + lane * 3;
    float4 a = xr[0], b = xr[1], c = xr[2];
    float s = a.x*a.x + a.y*a.y + a.z*a.z + a.w*a.w
            + b.x*b.x + b.y*b.y + b.z*b.z + b.w*b.w
            + c.x*c.x + c.y*c.y + c.z*c.z + c.w*c.w;
#pragma unroll
    for (int m = 32; m >= 1; m >>= 1) s += __shfl_xor(s, m);
    const float n = sqrtf(s);
    if (lane == 0) norms[row] = n;
    const float rn = 1.0f / fmaxf(n, KEPS);
    float v[12] = {a.x,a.y,a.z,a.w,b.x,b.y,b.z,b.w,c.x,c.y,c.z,c.w};
    uint8_t q[12];
#pragma unroll
    for (int i = 0; i < 12; ++i) q[i] = f2fp8(v[i] * rn);
    uint32_t* lb = (uint32_t*)&buf[wid][lane * 12];
    lb[0] = (uint32_t)q[0] | ((uint32_t)q[1] << 8) | ((uint32_t)q[2]  << 16) | ((uint32_t)q[3]  << 24);
    lb[1] = (uint32_t)q[4] | ((uint32_t)q[5] << 8) | ((uint32_t)q[6]  << 16) | ((uint32_t)q[7]  << 24);
    lb[2] = (uint32_t)q[8] | ((uint32_t)q[9] << 8) | ((uint32_t)q[10] << 16) | ((uint32_t)q[11] << 24);
    __syncthreads();
    if (lane < 48) {
        const int blk = lane >> 2;       // 64-k block 0..11
        const int h   = lane & 3;        // 8-k group within 32-k half
        const uint2 lo = *(const uint2*)&buf[wid][blk * 64 + h * 8];        // ks=0
        const uint2 hi = *(const uint2*)&buf[wid][blk * 64 + 32 + h * 8];   // ks=1
        *(uint4*)(Xn + (size_t)row * DIM + lane * 16) = make_uint4(lo.x, lo.y, hi.x, hi.y);
    }
}

// ---------------- Kernel 1b: init (value, index) max keys --------------------
__global__ __launch_bounds__(256) void k_init(unsigned long long* __restrict__ nn64) {
    nn64[blockIdx.x * 256 + threadIdx.x] = pack_vc(-2.0f, 0);
}

// ------ Kernel 2: fp8 128^2 upper-tri tile, BK=128 (6 rounds), 4 blk/CU ------
// Amortize the structural per-round stall (m233: stage+drain+barrier ~1100cyc
// survived R6/R9/R10 schedule variants): 2x MFMA per round, half the rounds.
// Plain mfma_f32_16x16x32_fp8_fp8 (R11's MX builtin spilled to scratch:
// WRITE_SIZE 82MB -> 2.2GB). Paired-ks b128 reads per 64-k half (R9 layout);
// chunk swizzle c^(r&7) over 8 chunks = b128 bank floor. LDS 32KB -> 4 blk/CU.
__global__ __launch_bounds__(256, 4) void k_maxdot(const uint8_t* __restrict__ Xn,
                                                   unsigned long long* __restrict__ nn64) {
    __shared__ uint8_t lA[BM * BK];
    __shared__ uint8_t lB[BM * BK];
    const int tid  = threadIdx.x;
    const int lane = tid & 63, wid = tid >> 6;
    const int wr = wid >> 1, wc = wid & 1;
    const int l15 = lane & 15, lhi = lane >> 4;

    // XCD-chunked bijective swizzle (NTILES % 8 == 0)
    int t = (int)blockIdx.x;
    t = (t & 7) * (NTILES / 8) + (t >> 3);
    // decode tile id -> (rb, cb), cb >= rb   [S(rb) = rb*(257-rb)/2]
    float disc = 66049.0f - 8.0f * (float)t;
    int rb = (int)((257.0f - sqrtf(disc)) * 0.5f);
    if (rb > NB - 1) rb = NB - 1;
    if (rb < 0) rb = 0;
    while (rb > 0 && rb * (257 - rb) / 2 > t) --rb;
    while ((rb + 1) * (257 - (rb + 1)) / 2 <= t) ++rb;
    const int cb = rb + (t - rb * (257 - rb) / 2);
    const int rowbase = rb * BM;
    const int colbase = cb * BM;
    const bool diag = (rb == cb);

    f32x4 acc[4][4];
    const f32x4 z = {0.f, 0.f, 0.f, 0.f};
#pragma unroll
    for (int i = 0; i < 4; ++i)
#pragma unroll
        for (int j = 0; j < 4; ++j) acc[i][j] = z;

    // staging: per panel 4 issues; r = it*32 + tid/8, chunk tid&7 (swizzled)
    const int s_r0 = tid >> 3;
    const int s_c  = tid & 7;

    for (int kt = 0; kt < KT; ++kt) {
#pragma unroll
        for (int it = 0; it < 4; ++it) {
            const int r = it * 32 + s_r0;
            const int c = s_c ^ (r & 7);
            const size_t koff = (size_t)kt * BK + c * 16;
            gload16(Xn + (size_t)(rowbase + r) * DIM + koff, lA + it * 4096 + tid * 16);
            gload16(Xn + (size_t)(colbase + r) * DIM + koff, lB + it * 4096 + tid * 16);
        }
        __syncthreads();     // single drain per 128-k round (was per 64-k)
#pragma unroll
        for (int ksp = 0; ksp < 2; ++ksp) {      // two 64-k halves
            long2_t afp[4], bgp[4];
#pragma unroll
            for (int mf = 0; mf < 4; ++mf) {
                const int r = wr * 64 + mf * 16 + l15;
                afp[mf] = *(const long2_t*)(lA + r * BK + (((ksp * 4 + lhi) ^ (r & 7)) << 4));
            }
#pragma unroll
            for (int nf = 0; nf < 4; ++nf) {
                const int r = wc * 64 + nf * 16 + l15;
                bgp[nf] = *(const long2_t*)(lB + r * BK + (((ksp * 4 + lhi) ^ (r & 7)) << 4));
            }
#pragma unroll
            for (int mf = 0; mf < 4; ++mf)
#pragma unroll
                for (int nf = 0; nf < 4; ++nf)
                    acc[mf][nf] = __builtin_amdgcn_mfma_f32_16x16x32_fp8_fp8(
                        afp[mf].x, bgp[nf].x, acc[mf][nf], 0, 0, 0);
#pragma unroll
            for (int mf = 0; mf < 4; ++mf)
#pragma unroll
                for (int nf = 0; nf < 4; ++nf)
                    acc[mf][nf] = __builtin_amdgcn_mfma_f32_16x16x32_fp8_fp8(
                        afp[mf].y, bgp[nf].y, acc[mf][nf], 0, 0, 0);
        }
        __syncthreads();
    }

    // diagonal tiles: mask self-similarity to -1 (reference semantics)
    if (diag) {
#pragma unroll
        for (int mf = 0; mf < 4; ++mf)
#pragma unroll
            for (int nf = 0; nf < 4; ++nf)
#pragma unroll
                for (int rr = 0; rr < 4; ++rr) {
                    const int rl = wr * 64 + mf * 16 + lhi * 4 + rr;
                    const int cl = wc * 64 + nf * 16 + l15;
                    if (rl == cl) acc[mf][nf][rr] = -1.0f;
                }
    }

    // ---- row-max with argmax col: nf regs -> 16 cols (lane bits 0..3) ----
#pragma unroll
    for (int mf = 0; mf < 4; ++mf)
#pragma unroll
        for (int rr = 0; rr < 4; ++rr) {
            float v = acc[mf][0][rr];
            int   c = colbase + wc * 64 + l15;
#pragma unroll
            for (int nf = 1; nf < 4; ++nf) {
                const float w2 = acc[mf][nf][rr];
                const int   c2 = colbase + wc * 64 + nf * 16 + l15;
                if (w2 > v) { v = w2; c = c2; }
            }
#pragma unroll
            for (int m = 1; m <= 8; m <<= 1) {
                const float ov = __shfl_xor(v, m);
                const int   oc = __shfl_xor(c, m);
                if (ov > v) { v = ov; c = oc; }
            }
            if (l15 == 0) {
                const int r = rowbase + wr * 64 + mf * 16 + lhi * 4 + rr;
                atomicMax(&nn64[r], pack_vc(v, c));
            }
        }

    // ---- col-max with argmax row: mf,rr regs -> row-groups (bits 4,5) ----
#pragma unroll
    for (int nf = 0; nf < 4; ++nf) {
        float v = acc[0][nf][0];
        int   c = rowbase + wr * 64 + lhi * 4;
#pragma unroll
        for (int mf = 0; mf < 4; ++mf)
#pragma unroll
            for (int rr = 0; rr < 4; ++rr) {
                if (mf == 0 && rr == 0) continue;
                const float w2 = acc[mf][nf][rr];
                const int   c2 = rowbase + wr * 64 + mf * 16 + lhi * 4 + rr;
                if (w2 > v) { v = w2; c = c2; }
            }
#pragma unroll
        for (int m = 16; m <= 32; m <<= 1) {
            const float ov = __shfl_xor(v, m);
            const int   oc = __shfl_xor(c, m);
            if (ov > v) { v = ov; c = oc; }
        }
        if ((lane >> 4) == 0) {
            const int cc = colbase + wc * 64 + nf * 16 + l15;
            atomicMax(&nn64[cc], pack_vc(v, c));
        }
    }
}

// --- Kernel 3: fp32 exact refine — reference distance for selected neighbor --
__global__ __launch_bounds__(256) void k_refine(const float* __restrict__ X,
                                                const float* __restrict__ norms,
                                                const unsigned long long* __restrict__ nn64,
                                                float* __restrict__ logd) {
    const int wid = threadIdx.x >> 6, lane = threadIdx.x & 63;
    const int r = blockIdx.x * 4 + wid;
    const int j = (int)(nn64[r] & 0xFFFFu);
    const float rnr = 1.0f / fmaxf(norms[r], KEPS);
    const float rnj = 1.0f / fmaxf(norms[j], KEPS);
    const float4* xr = (const float4*)(X + (size_t)r * DIM) + lane * 3;
    const float4* xj = (const float4*)(X + (size_t)j * DIM) + lane * 3;
    float s = 0.0f;
#pragma unroll
    for (int i = 0; i < 3; ++i) {
        const float4 a = xr[i], b = xj[i];
        float d;
        d = a.x * rnr - b.x * rnj + KEPS; s = fmaf(d, d, s);
        d = a.y * rnr - b.y * rnj + KEPS; s = fmaf(d, d, s);
        d = a.z * rnr - b.z * rnj + KEPS; s = fmaf(d, d, s);
        d = a.w * rnr - b.w * rnj + KEPS; s = fmaf(d, d, s);
    }
#pragma unroll
    for (int m = 32; m >= 1; m >>= 1) s += __shfl_xor(s, m);
    if (lane == 0) logd[r] = logf(sqrtf(s) + KEPS);
}

// ---------------- Kernel 4: deterministic mean of log-distances --------------
__global__ __launch_bounds__(256) void k_loss(const float* __restrict__ logd,
                                              float* __restrict__ out) {
    float local = 0.0f;
    for (int r = threadIdx.x; r < NR; r += 256) local += logd[r];
#pragma unroll
    for (int m = 32; m >= 1; m >>= 1) local += __shfl_xor(local, m);
    __shared__ float red[4];
    const int lane = threadIdx.x & 63, wid = threadIdx.x >> 6;
    if (lane == 0) red[wid] = local;
    __syncthreads();
    if (threadIdx.x == 0)
        out[0] = -(red[0] + red[1] + red[2] + red[3]) / (float)NR;
}

extern "C" void kernel_launch(void* const* d_in, const int* in_sizes, int n_in,
                              void* d_out, int out_size, void* d_ws, size_t ws_size,
                              hipStream_t stream) {
    const float* X = (const float*)d_in[0];
    float* out = (float*)d_out;
    uint8_t* Xn = (uint8_t*)d_ws;                                  // 12.6 MiB fp8
    char* p = (char*)d_ws + (size_t)NR * DIM;
    float* norms = (float*)p;                 p += (size_t)NR * 4;
    unsigned long long* nn64 = (unsigned long long*)p; p += (size_t)NR * 8;
    float* logd = (float*)p;

    k_norm<<<NR / 4, 256, 0, stream>>>(X, Xn, norms);
    k_init<<<NR / 256, 256, 0, stream>>>(nn64);
    k_maxdot<<<NTILES, 256, 0, stream>>>(Xn, nn64);
    k_refine<<<NR / 4, 256, 0, stream>>>(X, norms, nn64, logd);
    k_loss<<<1, 256, 0, stream>>>(logd, out);
}

// Round 13
// 307.853 us; speedup vs baseline: 3.6245x; 1.0238x over previous
//
#include <hip/hip_runtime.h>
#include <hip/hip_bf16.h>
#include <stdint.h>
#include <math.h>

#define NR 16384
#define DIM 768
#define KEPS 1e-8f

#define BM 128          // tile edge
#define NB (NR / BM)    // 128 row/col panels
#define KT (DIM / 64)   // 12 k-steps of 64
#define NQ (DIM / 16)   // 48 16B chunks per row
#define NTILES (NB * (NB + 1) / 2)   // 8256 upper-triangle tiles

typedef __attribute__((ext_vector_type(4))) float f32x4;
typedef __attribute__((ext_vector_type(2))) long long2_t;

__device__ inline uint32_t fkey(float f) {
    union { float f; uint32_t u; } v; v.f = f;
    return (v.u & 0x80000000u) ? ~v.u : (v.u | 0x80000000u);
}

__device__ inline unsigned long long pack_vc(float v, int c) {
    return ((unsigned long long)fkey(v) << 32) | (unsigned)c;
}

// fp32 -> OCP e4m3fn (selection only; refine pass recomputes exact fp32)
__device__ inline uint8_t f2fp8(float f) {
    union { float f; uint32_t u; } v; v.f = f;
    const uint8_t s = (uint8_t)((v.u >> 24) & 0x80u);
    float a = fabsf(f);
    if (a >= 448.0f) return s | 0x7E;
    if (a < 0.015625f) {
        int q = (int)rintf(a * 512.0f);
        if (q >= 8) return s | 0x08;
        return s | (uint8_t)q;
    }
    int ex; float m = frexpf(a, &ex);
    int E = ex + 6;
    int frac = (int)rintf(m * 16.0f - 8.0f);
    if (frac >= 8) { frac = 0; ++E; if (E > 15) return s | 0x7E; }
    return s | (uint8_t)(E << 3) | (uint8_t)frac;
}

// ---- Kernel 1: L2-normalize -> fp8, write panel-blocked TRANSPOSED layout ---
// XnT[panel p][chunk q 0..47][row r 0..127] : 16B chunk; within each 64-k
// block the ks-pairing permutation (orig byte ks*32+h*8+b -> h*16+ks*8+b)
// makes chunk q = kt*4+h hold a lane's ks0+ks1 MFMA fragments contiguously.
// Fragment loads in k_maxdot then read 16 rows x 16B = 256B contiguous.
__global__ __launch_bounds__(256) void k_norm(const float* __restrict__ X,
                                              uint8_t* __restrict__ XnT,
                                              float* __restrict__ norms) {
    __shared__ uint8_t buf[4][768];
    const int wid = threadIdx.x >> 6, lane = threadIdx.x & 63;
    const int row = blockIdx.x * 4 + wid;
    const float4* xr = (const float4*)(X + (size_t)row * DIM) + lane * 3;
    float4 a = xr[0], b = xr[1], c = xr[2];
    float s = a.x*a.x + a.y*a.y + a.z*a.z + a.w*a.w
            + b.x*b.x + b.y*b.y + b.z*b.z + b.w*b.w
            + c.x*c.x + c.y*c.y + c.z*c.z + c.w*c.w;
#pragma unroll
    for (int m = 32; m >= 1; m >>= 1) s += __shfl_xor(s, m);
    const float n = sqrtf(s);
    if (lane == 0) norms[row] = n;
    const float rn = 1.0f / fmaxf(n, KEPS);
    float v[12] = {a.x,a.y,a.z,a.w,b.x,b.y,b.z,b.w,c.x,c.y,c.z,c.w};
    uint8_t q[12];
#pragma unroll
    for (int i = 0; i < 12; ++i) q[i] = f2fp8(v[i] * rn);
    uint32_t* lb = (uint32_t*)&buf[wid][lane * 12];
    lb[0] = (uint32_t)q[0] | ((uint32_t)q[1] << 8) | ((uint32_t)q[2]  << 16) | ((uint32_t)q[3]  << 24);
    lb[1] = (uint32_t)q[4] | ((uint32_t)q[5] << 8) | ((uint32_t)q[6]  << 16) | ((uint32_t)q[7]  << 24);
    lb[2] = (uint32_t)q[8] | ((uint32_t)q[9] << 8) | ((uint32_t)q[10] << 16) | ((uint32_t)q[11] << 24);
    __syncthreads();
    if (lane < NQ) {
        const int blk = lane >> 2;       // 64-k block 0..11
        const int h   = lane & 3;        // 8-k group within 32-k half
        const uint2 lo = *(const uint2*)&buf[wid][blk * 64 + h * 8];        // ks=0
        const uint2 hi = *(const uint2*)&buf[wid][blk * 64 + 32 + h * 8];   // ks=1
        const size_t off = ((size_t)(row >> 7) * NQ * 128 + (size_t)lane * 128
                            + (row & 127)) * 16;
        *(uint4*)(XnT + off) = make_uint4(lo.x, lo.y, hi.x, hi.y);
    }
}

// ---------------- Kernel 1b: init (value, index) max keys --------------------
__global__ __launch_bounds__(256) void k_init(unsigned long long* __restrict__ nn64) {
    nn64[blockIdx.x * 256 + threadIdx.x] = pack_vc(-2.0f, 0);
}

// ---- Kernel 2: fp8 128^2 upper-tri tile, NO LDS / NO barriers ---------------
// Xn (12.6 MB) is L2/L3-resident; LDS reuse per block was only 2x -> staging
// was pure overhead (Common-mistake #7). Fragments load straight to VGPR from
// the blocked-transposed layout: one global_load_dwordx4 per fragment = four
// 256B contiguous segments. Waves fully decoupled; latency hidden by
// 3 waves/SIMD and the compiler's software pipelining (no barrier lockstep).
__global__ __launch_bounds__(256, 3) void k_maxdot(const uint8_t* __restrict__ XnT,
                                                   unsigned long long* __restrict__ nn64) {
    const int tid  = threadIdx.x;
    const int lane = tid & 63, wid = tid >> 6;
    const int wr = wid >> 1, wc = wid & 1;
    const int l15 = lane & 15, lhi = lane >> 4;

    // XCD-chunked bijective swizzle (NTILES % 8 == 0)
    int t = (int)blockIdx.x;
    t = (t & 7) * (NTILES / 8) + (t >> 3);
    // decode tile id -> (rb, cb), cb >= rb   [S(rb) = rb*(257-rb)/2]
    float disc = 66049.0f - 8.0f * (float)t;
    int rb = (int)((257.0f - sqrtf(disc)) * 0.5f);
    if (rb > NB - 1) rb = NB - 1;
    if (rb < 0) rb = 0;
    while (rb > 0 && rb * (257 - rb) / 2 > t) --rb;
    while ((rb + 1) * (257 - (rb + 1)) / 2 <= t) ++rb;
    const int cb = rb + (t - rb * (257 - rb) / 2);
    const int rowbase = rb * BM;
    const int colbase = cb * BM;
    const bool diag = (rb == cb);

    // panel bases in the transposed layout (panel index == rb/cb)
    const uint8_t* pA = XnT + (size_t)rb * NQ * 128 * 16;
    const uint8_t* pB = XnT + (size_t)cb * NQ * 128 * 16;

    f32x4 acc[4][4];
    const f32x4 z = {0.f, 0.f, 0.f, 0.f};
#pragma unroll
    for (int i = 0; i < 4; ++i)
#pragma unroll
        for (int j = 0; j < 4; ++j) acc[i][j] = z;

    // per kt: chunk q = kt*4 + lhi; fragment addr = panel + (q*128 + row)*16
    const int arow = wr * 64 + l15;     // + mf*16
    const int brow = wc * 64 + l15;     // + nf*16
#pragma unroll 2
    for (int kt = 0; kt < KT; ++kt) {
        const size_t qoff = (size_t)(kt * 4 + lhi) * 128 * 16;
        long2_t af[4], bg[4];
#pragma unroll
        for (int mf = 0; mf < 4; ++mf)
            af[mf] = *(const long2_t*)(pA + qoff + (size_t)(arow + mf * 16) * 16);
#pragma unroll
        for (int nf = 0; nf < 4; ++nf)
            bg[nf] = *(const long2_t*)(pB + qoff + (size_t)(brow + nf * 16) * 16);
#pragma unroll
        for (int mf = 0; mf < 4; ++mf)
#pragma unroll
            for (int nf = 0; nf < 4; ++nf)
                acc[mf][nf] = __builtin_amdgcn_mfma_f32_16x16x32_fp8_fp8(
                    af[mf].x, bg[nf].x, acc[mf][nf], 0, 0, 0);
#pragma unroll
        for (int mf = 0; mf < 4; ++mf)
#pragma unroll
            for (int nf = 0; nf < 4; ++nf)
                acc[mf][nf] = __builtin_amdgcn_mfma_f32_16x16x32_fp8_fp8(
                    af[mf].y, bg[nf].y, acc[mf][nf], 0, 0, 0);
    }

    // diagonal tiles: mask self-similarity to -1 (reference semantics)
    if (diag) {
#pragma unroll
        for (int mf = 0; mf < 4; ++mf)
#pragma unroll
            for (int nf = 0; nf < 4; ++nf)
#pragma unroll
                for (int rr = 0; rr < 4; ++rr) {
                    const int rl = wr * 64 + mf * 16 + lhi * 4 + rr;
                    const int cl = wc * 64 + nf * 16 + l15;
                    if (rl == cl) acc[mf][nf][rr] = -1.0f;
                }
    }

    // ---- row-max with argmax col: nf regs -> 16 cols (lane bits 0..3) ----
#pragma unroll
    for (int mf = 0; mf < 4; ++mf)
#pragma unroll
        for (int rr = 0; rr < 4; ++rr) {
            float v = acc[mf][0][rr];
            int   c = colbase + wc * 64 + l15;
#pragma unroll
            for (int nf = 1; nf < 4; ++nf) {
                const float w2 = acc[mf][nf][rr];
                const int   c2 = colbase + wc * 64 + nf * 16 + l15;
                if (w2 > v) { v = w2; c = c2; }
            }
#pragma unroll
            for (int m = 1; m <= 8; m <<= 1) {
                const float ov = __shfl_xor(v, m);
                const int   oc = __shfl_xor(c, m);
                if (ov > v) { v = ov; c = oc; }
            }
            if (l15 == 0) {
                const int r = rowbase + wr * 64 + mf * 16 + lhi * 4 + rr;
                atomicMax(&nn64[r], pack_vc(v, c));
            }
        }

    // ---- col-max with argmax row: mf,rr regs -> row-groups (bits 4,5) ----
#pragma unroll
    for (int nf = 0; nf < 4; ++nf) {
        float v = acc[0][nf][0];
        int   c = rowbase + wr * 64 + lhi * 4;
#pragma unroll
        for (int mf = 0; mf < 4; ++mf)
#pragma unroll
            for (int rr = 0; rr < 4; ++rr) {
                if (mf == 0 && rr == 0) continue;
                const float w2 = acc[mf][nf][rr];
                const int   c2 = rowbase + wr * 64 + mf * 16 + lhi * 4 + rr;
                if (w2 > v) { v = w2; c = c2; }
            }
#pragma unroll
        for (int m = 16; m <= 32; m <<= 1) {
            const float ov = __shfl_xor(v, m);
            const int   oc = __shfl_xor(c, m);
            if (ov > v) { v = ov; c = oc; }
        }
        if ((lane >> 4) == 0) {
            const int cc = colbase + wc * 64 + nf * 16 + l15;
            atomicMax(&nn64[cc], pack_vc(v, c));
        }
    }
}

// --- Kernel 3: fp32 exact refine — reference distance for selected neighbor --
__global__ __launch_bounds__(256) void k_refine(const float* __restrict__ X,
                                                const float* __restrict__ norms,
                                                const unsigned long long* __restrict__ nn64,
                                                float* __restrict__ logd) {
    const int wid = threadIdx.x >> 6, lane = threadIdx.x & 63;
    const int r = blockIdx.x * 4 + wid;
    const int j = (int)(nn64[r] & 0xFFFFu);
    const float rnr = 1.0f / fmaxf(norms[r], KEPS);
    const float rnj = 1.0f / fmaxf(norms[j], KEPS);
    const float4* xr = (const float4*)(X + (size_t)r * DIM) + lane * 3;
    const float4* xj = (const float4*)(X + (size_t)j * DIM) + lane * 3;
    float s = 0.0f;
#pragma unroll
    for (int i = 0; i < 3; ++i) {
        const float4 a = xr[i], b = xj[i];
        float d;
        d = a.x * rnr - b.x * rnj + KEPS; s = fmaf(d, d, s);
        d = a.y * rnr - b.y * rnj + KEPS; s = fmaf(d, d, s);
        d = a.z * rnr - b.z * rnj + KEPS; s = fmaf(d, d, s);
        d = a.w * rnr - b.w * rnj + KEPS; s = fmaf(d, d, s);
    }
#pragma unroll
    for (int m = 32; m >= 1; m >>= 1) s += __shfl_xor(s, m);
    if (lane == 0) logd[r] = logf(sqrtf(s) + KEPS);
}

// ---------------- Kernel 4: deterministic mean of log-distances --------------
__global__ __launch_bounds__(256) void k_loss(const float* __restrict__ logd,
                                              float* __restrict__ out) {
    float local = 0.0f;
    for (int r = threadIdx.x; r < NR; r += 256) local += logd[r];
#pragma unroll
    for (int m = 32; m >= 1; m >>= 1) local += __shfl_xor(local, m);
    __shared__ float red[4];
    const int lane = threadIdx.x & 63, wid = threadIdx.x >> 6;
    if (lane == 0) red[wid] = local;
    __syncthreads();
    if (threadIdx.x == 0)
        out[0] = -(red[0] + red[1] + red[2] + red[3]) / (float)NR;
}

extern "C" void kernel_launch(void* const* d_in, const int* in_sizes, int n_in,
                              void* d_out, int out_size, void* d_ws, size_t ws_size,
                              hipStream_t stream) {
    const float* X = (const float*)d_in[0];
    float* out = (float*)d_out;
    uint8_t* XnT = (uint8_t*)d_ws;                                 // 12.6 MiB fp8 (transposed)
    char* p = (char*)d_ws + (size_t)NR * DIM;
    float* norms = (float*)p;                 p += (size_t)NR * 4;
    unsigned long long* nn64 = (unsigned long long*)p; p += (size_t)NR * 8;
    float* logd = (float*)p;

    k_norm<<<NR / 4, 256, 0, stream>>>(X, XnT, norms);
    k_init<<<NR / 256, 256, 0, stream>>>(nn64);
    k_maxdot<<<NTILES, 256, 0, stream>>>(XnT, nn64);
    k_refine<<<NR / 4, 256, 0, stream>>>(X, norms, nn64, logd);
    k_loss<<<1, 256, 0, stream>>>(logd, out);
}